// Round 4
// baseline (256.751 us; speedup 1.0000x reference)
//
#include <hip/hip_runtime.h>
#include <cstdint>
#include <cstddef>

typedef int int32x4  __attribute__((ext_vector_type(4)));
typedef int int32x16 __attribute__((ext_vector_type(16)));

#define AS1 __attribute__((address_space(1)))
#define AS3 __attribute__((address_space(3)))

__device__ __forceinline__ void gload_lds16(const void* g, void* l) {
    __builtin_amdgcn_global_load_lds((const AS1 void*)g, (AS3 void*)l, 16, 0, 0);
}

// ---------------------------------------------------------------------------
// Kernel 1: x (fp32, int8-valued) -> A8 (int8) + row sums rs.
// One block per row. Fully coalesced: loads 1KB/wave-instr, stores 256B.
// ---------------------------------------------------------------------------
__global__ __launch_bounds__(256) void quant_x(const float* __restrict__ x,
                                               signed char* __restrict__ A8,
                                               int* __restrict__ rs) {
    const int row = blockIdx.x;
    const int t = threadIdx.x;
    const float4* xr = (const float4*)(x + (size_t)row * 4096);
    char4* ar = (char4*)(A8 + (size_t)row * 4096);
    int s = 0;
#pragma unroll
    for (int i = 0; i < 4; i++) {
        const int idx = i * 256 + t;
        float4 v = xr[idx];
        int a0 = (int)v.x, a1 = (int)v.y, a2 = (int)v.z, a3 = (int)v.w;
        s += a0 + a1 + a2 + a3;
        char4 c;
        c.x = (signed char)a0; c.y = (signed char)a1;
        c.z = (signed char)a2; c.w = (signed char)a3;
        ar[idx] = c;
    }
#pragma unroll
    for (int off = 32; off > 0; off >>= 1) s += __shfl_down(s, off);
    __shared__ int wsum[4];
    if ((t & 63) == 0) wsum[t >> 6] = s;
    __syncthreads();
    if (t == 0) rs[row] = wsum[0] + wsum[1] + wsum[2] + wsum[3];
}

// ---------------------------------------------------------------------------
// Kernel 2: y (fp32, uint8-valued) -> B8T (int8 transposed, y-128) + col sums
// sy (fused; sy pre-zeroed by memset). 64k x 64n tile per block via LDS
// byte-transpose (pitch 68 -> <=2-way banks). Stores: int4, adjacent-lane
// quads cover each output row's 64B in order.
// ---------------------------------------------------------------------------
__global__ __launch_bounds__(256) void quant_y(const float* __restrict__ y,
                                               signed char* __restrict__ B8T,
                                               int* __restrict__ sy) {
    __shared__ __align__(16) signed char tile[64 * 68];  // tile[n*68 + k]
    __shared__ int ssum[64];
    const int nt = blockIdx.x * 64;
    const int kt = blockIdx.y * 64;
    const int t = threadIdx.x;
    if (t < 64) ssum[t] = 0;
    __syncthreads();

    const int r0 = t >> 4;         // k-offset within tile group
    const int c4 = (t & 15) * 4;   // n-offset (4 cols per thread)
    int s0 = 0, s1 = 0, s2 = 0, s3 = 0;
#pragma unroll
    for (int i = 0; i < 4; i++) {
        const int k = i * 16 + r0;
        float4 v = *(const float4*)(y + (size_t)(kt + k) * 4096 + nt + c4);
        int b0 = (int)v.x - 128, b1 = (int)v.y - 128;
        int b2 = (int)v.z - 128, b3 = (int)v.w - 128;
        s0 += b0; s1 += b1; s2 += b2; s3 += b3;
        tile[(c4 + 0) * 68 + k] = (signed char)b0;
        tile[(c4 + 1) * 68 + k] = (signed char)b1;
        tile[(c4 + 2) * 68 + k] = (signed char)b2;
        tile[(c4 + 3) * 68 + k] = (signed char)b3;
    }
    atomicAdd(&ssum[c4 + 0], s0);
    atomicAdd(&ssum[c4 + 1], s1);
    atomicAdd(&ssum[c4 + 2], s2);
    atomicAdd(&ssum[c4 + 3], s3);
    __syncthreads();

    const int n = t >> 2;          // output row within tile
    const int kc = (t & 3) * 16;   // 16B chunk within row
    const signed char* src = tile + n * 68 + kc;
    int32x4 w;
    w.x = *(const int*)(src + 0);
    w.y = *(const int*)(src + 4);
    w.z = *(const int*)(src + 8);
    w.w = *(const int*)(src + 12);
    *(int32x4*)(B8T + (size_t)(nt + n) * 4096 + kt + kc) = w;
    if (t < 64) atomicAdd(&sy[nt + t], ssum[t]);
}

// ---------------------------------------------------------------------------
// Kernel 3: int8 GEMM. 128x128 block tile, BK=64, 4 waves (2x2), each wave a
// 64x64 tile = 2x2 grid of 32x32x32 i8 MFMAs x 2 k-steps. Double-buffered
// LDS (32 KB), ONE barrier per BK-iter: stage tile k+1 before computing
// tile k so the vmcnt(0) drain at the barrier overlaps compute.
// LDS layout: dense 64B rows, XOR chunk swizzle slot = chunk ^ ((row>>1)&3)
// -> staging keeps adjacent-quad global coalescing (chunks permuted within
// one 64B segment) and every 8-lane phase of the b128 fragment reads covers
// all 32 banks exactly once (zero conflicts).
// 32x32x32_i8 fragments: A[m=lane&31][k=(lane>>5)*16+j]; B symmetric on B^T
// rows; C/D col=lane&31, row=(reg&3)+8*(reg>>2)+4*(lane>>5).
// Epilogue: C = 7.5e-4 * (P - 32*rs[m] + 66*sy[n] - 8650752)
// ---------------------------------------------------------------------------
__global__ __launch_bounds__(256, 4) void gemm_i8(const signed char* __restrict__ A8,
                                                  const signed char* __restrict__ B8T,
                                                  const int* __restrict__ rs,
                                                  const int* __restrict__ sy,
                                                  float* __restrict__ C) {
    __shared__ __align__(16) signed char As[2 * 8192];  // 16 KB (2 bufs)
    __shared__ __align__(16) signed char Bs[2 * 8192];  // 16 KB
    const int tid = threadIdx.x;
    const int bm = blockIdx.y * 128;
    const int bn = blockIdx.x * 128;
    const int lane = tid & 63;
    const int wave = tid >> 6;
    const int wm = (wave >> 1) * 64;
    const int wn = (wave & 1) * 64;
    const int mr = lane & 31;   // m/n row within 32x32 tile
    const int kh = lane >> 5;   // k-half (which 16B of K=32)

    int32x16 acc[2][2] = {};

    // staging: thread tid -> row tid>>2 (adjacent quads), global chunk
    // (tid&3)^((tid>>3)&3) lands at phys slot tid&3 (XOR swizzle).
    const int srow = tid >> 2;
    const int scol = ((tid & 3) ^ ((tid >> 3) & 3)) * 16;
    const size_t arow  = (size_t)(bm + srow) * 4096 + scol;
    const size_t brow  = (size_t)(bn + srow) * 4096 + scol;
    const size_t arow2 = arow + (size_t)64 * 4096;
    const size_t brow2 = brow + (size_t)64 * 4096;

    // fragment LDS offsets (K-loop invariant):
    // row = wtile + i*32 + mr; chunk = ks*2 + kh; slot = chunk ^ ((mr>>1)&3)
    int aoff[2][2], boff[2][2];
#pragma unroll
    for (int i = 0; i < 2; i++)
#pragma unroll
        for (int ks = 0; ks < 2; ks++) {
            const int slot = ((ks * 2 + kh) ^ ((mr >> 1) & 3)) * 16;
            aoff[i][ks] = (wm + i * 32 + mr) * 64 + slot;
            boff[i][ks] = (wn + i * 32 + mr) * 64 + slot;
        }

    auto stage = [&](int buf, int kt) {
        signed char* a_dst = As + buf * 8192 + tid * 16;
        signed char* b_dst = Bs + buf * 8192 + tid * 16;
        gload_lds16(A8 + arow + kt, a_dst);
        gload_lds16(A8 + arow2 + kt, a_dst + 4096);
        gload_lds16(B8T + brow + kt, b_dst);
        gload_lds16(B8T + brow2 + kt, b_dst + 4096);
    };
    auto compute = [&](int buf) {
        const signed char* Ab = As + buf * 8192;
        const signed char* Bb = Bs + buf * 8192;
#pragma unroll
        for (int ks = 0; ks < 2; ks++) {
            int32x4 af[2], bf[2];
#pragma unroll
            for (int i = 0; i < 2; i++) af[i] = *(const int32x4*)(Ab + aoff[i][ks]);
#pragma unroll
            for (int j = 0; j < 2; j++) bf[j] = *(const int32x4*)(Bb + boff[j][ks]);
#pragma unroll
            for (int i = 0; i < 2; i++)
#pragma unroll
                for (int j = 0; j < 2; j++)
                    acc[i][j] = __builtin_amdgcn_mfma_i32_32x32x32_i8(af[i], bf[j], acc[i][j], 0, 0, 0);
        }
    };

    stage(0, 0);
    __syncthreads();
#pragma unroll 1
    for (int kt = 0; kt < 4096; kt += 128) {
        stage(1, kt + 64);
        compute(0);
        __syncthreads();
        if (kt + 128 < 4096) stage(0, kt + 128);
        compute(1);
        __syncthreads();
    }

    // Epilogue. C/D: col = lane&31, row = (reg&3) + 8*(reg>>2) + 4*kh
#pragma unroll
    for (int i = 0; i < 2; i++) {
#pragma unroll
        for (int r = 0; r < 16; r++) {
            const int gm = bm + wm + i * 32 + (r & 3) + 8 * (r >> 2) + 4 * kh;
            const int rcorr = -32 * rs[gm] - 8650752;
#pragma unroll
            for (int j = 0; j < 2; j++) {
                const int gn = bn + wn + j * 32 + mr;
                const int v = acc[i][j][r] + rcorr + 66 * sy[gn];
                C[(size_t)gm * 4096 + gn] = 7.5e-4f * (float)v;
            }
        }
    }
}

// ---------------------------------------------------------------------------
extern "C" void kernel_launch(void* const* d_in, const int* in_sizes, int n_in,
                              void* d_out, int out_size, void* d_ws, size_t ws_size,
                              hipStream_t stream) {
    const float* x = (const float*)d_in[0];  // [4096,4096] int8-valued
    const float* y = (const float*)d_in[1];  // [4096,4096] uint8-valued
    float* out = (float*)d_out;

    char* ws = (char*)d_ws;
    signed char* A8  = (signed char*)ws;                         // 16 MiB
    signed char* B8T = (signed char*)(ws + (16u << 20));         // 16 MiB
    int* rs = (int*)(ws + (32u << 20));                          // 16 KiB
    int* sy = (int*)(ws + (32u << 20) + (16u << 10));            // 16 KiB

    hipMemsetAsync(sy, 0, 4096 * sizeof(int), stream);
    quant_x<<<4096, 256, 0, stream>>>(x, A8, rs);
    quant_y<<<dim3(64, 64), 256, 0, stream>>>(y, B8T, sy);
    gemm_i8<<<dim3(32, 32), 256, 0, stream>>>(A8, B8T, rs, sy, out);
}

// Round 5
// 254.523 us; speedup vs baseline: 1.0088x; 1.0088x over previous
//
#include <hip/hip_runtime.h>
#include <cstdint>
#include <cstddef>

typedef int int32x4  __attribute__((ext_vector_type(4)));
typedef int int32x16 __attribute__((ext_vector_type(16)));

#define AS1 __attribute__((address_space(1)))
#define AS3 __attribute__((address_space(3)))

__device__ __forceinline__ void gload_lds16(const void* g, void* l) {
    __builtin_amdgcn_global_load_lds((const AS1 void*)g, (AS3 void*)l, 16, 0, 0);
}

// ---------------------------------------------------------------------------
// Kernel 1: x (fp32, int8-valued) -> A8 (int8) + row sums rs.
// One block per row. Fully coalesced: loads 1KB/wave-instr, stores 256B.
// ---------------------------------------------------------------------------
__global__ __launch_bounds__(256) void quant_x(const float* __restrict__ x,
                                               signed char* __restrict__ A8,
                                               int* __restrict__ rs) {
    const int row = blockIdx.x;
    const int t = threadIdx.x;
    const float4* xr = (const float4*)(x + (size_t)row * 4096);
    char4* ar = (char4*)(A8 + (size_t)row * 4096);
    int s = 0;
#pragma unroll
    for (int i = 0; i < 4; i++) {
        const int idx = i * 256 + t;
        float4 v = xr[idx];
        int a0 = (int)v.x, a1 = (int)v.y, a2 = (int)v.z, a3 = (int)v.w;
        s += a0 + a1 + a2 + a3;
        char4 c;
        c.x = (signed char)a0; c.y = (signed char)a1;
        c.z = (signed char)a2; c.w = (signed char)a3;
        ar[idx] = c;
    }
#pragma unroll
    for (int off = 32; off > 0; off >>= 1) s += __shfl_down(s, off);
    __shared__ int wsum[4];
    if ((t & 63) == 0) wsum[t >> 6] = s;
    __syncthreads();
    if (t == 0) rs[row] = wsum[0] + wsum[1] + wsum[2] + wsum[3];
}

// ---------------------------------------------------------------------------
// Kernel 2: y (fp32, uint8-valued) -> B8T (int8 transposed, y-128) + col sums
// sy (fused; sy pre-zeroed by memset). 64k x 64n tile per block via LDS
// byte-transpose (pitch 68 -> <=2-way banks). Stores: int4, adjacent-lane
// quads cover each output row's 64B in order.
// ---------------------------------------------------------------------------
__global__ __launch_bounds__(256) void quant_y(const float* __restrict__ y,
                                               signed char* __restrict__ B8T,
                                               int* __restrict__ sy) {
    __shared__ __align__(16) signed char tile[64 * 68];  // tile[n*68 + k]
    __shared__ int ssum[64];
    const int nt = blockIdx.x * 64;
    const int kt = blockIdx.y * 64;
    const int t = threadIdx.x;
    if (t < 64) ssum[t] = 0;
    __syncthreads();

    const int r0 = t >> 4;         // k-offset within tile group
    const int c4 = (t & 15) * 4;   // n-offset (4 cols per thread)
    int s0 = 0, s1 = 0, s2 = 0, s3 = 0;
#pragma unroll
    for (int i = 0; i < 4; i++) {
        const int k = i * 16 + r0;
        float4 v = *(const float4*)(y + (size_t)(kt + k) * 4096 + nt + c4);
        int b0 = (int)v.x - 128, b1 = (int)v.y - 128;
        int b2 = (int)v.z - 128, b3 = (int)v.w - 128;
        s0 += b0; s1 += b1; s2 += b2; s3 += b3;
        tile[(c4 + 0) * 68 + k] = (signed char)b0;
        tile[(c4 + 1) * 68 + k] = (signed char)b1;
        tile[(c4 + 2) * 68 + k] = (signed char)b2;
        tile[(c4 + 3) * 68 + k] = (signed char)b3;
    }
    atomicAdd(&ssum[c4 + 0], s0);
    atomicAdd(&ssum[c4 + 1], s1);
    atomicAdd(&ssum[c4 + 2], s2);
    atomicAdd(&ssum[c4 + 3], s3);
    __syncthreads();

    const int n = t >> 2;          // output row within tile
    const int kc = (t & 3) * 16;   // 16B chunk within row
    const signed char* src = tile + n * 68 + kc;
    int32x4 w;
    w.x = *(const int*)(src + 0);
    w.y = *(const int*)(src + 4);
    w.z = *(const int*)(src + 8);
    w.w = *(const int*)(src + 12);
    *(int32x4*)(B8T + (size_t)(nt + n) * 4096 + kt + kc) = w;
    if (t < 64) atomicAdd(&sy[nt + t], ssum[t]);
}

// ---------------------------------------------------------------------------
// Kernel 3: int8 GEMM. Block tile 256(M) x 128(N), BK=64, 4 waves in 2x2,
// wave tile 128x64 = 4x2 grid of 32x32x32 i8 MFMAs. Rationale: LDS-read
// bytes/MAC = (tm+tn)/(tm*tn*32); 4x2 gives 0.0234 vs 2x2's 0.0313 ->
// LDS port (85B/cyc, the round-4 ceiling) now balanced with matrix pipe.
// Double-buffered LDS (48KB), stage-ahead, one barrier per BK tile.
// LDS layout: dense 64B rows, XOR chunk swizzle slot = chunk ^ ((row>>1)&3)
// (throughput-balanced banks for both staging and fragment reads).
// 32x32x32_i8 frags: A[m=lane&31][k=(lane>>5)*16+j]; C/D col=lane&31,
// row=(reg&3)+8*(reg>>2)+4*(lane>>5)  (verified rounds 1-4, absmax 32).
// Epilogue: C = 7.5e-4 * (P - 32*rs[m] + 66*sy[n] - 8650752)
// ---------------------------------------------------------------------------
__global__ __launch_bounds__(256, 2) void gemm_i8(const signed char* __restrict__ A8,
                                                  const signed char* __restrict__ B8T,
                                                  const int* __restrict__ rs,
                                                  const int* __restrict__ sy,
                                                  float* __restrict__ C) {
    __shared__ __align__(16) signed char As[2 * 16384];  // 256 rows x 64B, dbuf
    __shared__ __align__(16) signed char Bs[2 * 8192];   // 128 rows x 64B, dbuf
    const int tid = threadIdx.x;
    const int bm = blockIdx.y * 256;
    const int bn = blockIdx.x * 128;
    const int lane = tid & 63;
    const int wave = tid >> 6;
    const int wm = (wave >> 1) * 128;   // 2 m-waves x 128
    const int wn = (wave & 1) * 64;     // 2 n-waves x 64
    const int mr = lane & 31;           // row within 32x32 tile
    const int kh = lane >> 5;           // k-half (which 16B of K=32)

    int32x16 acc[4][2] = {};

    // staging: thread tid -> row (tid>>2) + 64*p (adjacent quads), global
    // chunk (tid&3)^((tid>>3)&3) lands at phys slot tid&3 (XOR swizzle; the
    // row-dependent term ((row>>1)&3) is invariant under row += 64).
    const int srow = tid >> 2;
    const int scol = ((tid & 3) ^ ((tid >> 3) & 3)) * 16;
    const size_t arow = (size_t)(bm + srow) * 4096 + scol;
    const size_t brow = (size_t)(bn + srow) * 4096 + scol;

    // fragment LDS offsets (K-loop invariant):
    // row = wtile + i*32 + mr; chunk = ks*2 + kh; slot = chunk ^ ((mr>>1)&3)
    int aoff[4][2], boff[2][2];
#pragma unroll
    for (int ks = 0; ks < 2; ks++) {
        const int slot = ((ks * 2 + kh) ^ ((mr >> 1) & 3)) * 16;
#pragma unroll
        for (int i = 0; i < 4; i++) aoff[i][ks] = (wm + i * 32 + mr) * 64 + slot;
#pragma unroll
        for (int j = 0; j < 2; j++) boff[j][ks] = (wn + j * 32 + mr) * 64 + slot;
    }

    auto stage = [&](int buf, int kt) {
        signed char* a_dst = As + buf * 16384 + tid * 16;
        signed char* b_dst = Bs + buf * 8192 + tid * 16;
#pragma unroll
        for (int p = 0; p < 4; p++)
            gload_lds16(A8 + arow + (size_t)p * 64 * 4096 + kt, a_dst + p * 4096);
#pragma unroll
        for (int p = 0; p < 2; p++)
            gload_lds16(B8T + brow + (size_t)p * 64 * 4096 + kt, b_dst + p * 4096);
    };
    auto compute = [&](int buf) {
        const signed char* Ab = As + buf * 16384;
        const signed char* Bb = Bs + buf * 8192;
#pragma unroll
        for (int ks = 0; ks < 2; ks++) {
            int32x4 af[4], bf[2];
#pragma unroll
            for (int i = 0; i < 4; i++) af[i] = *(const int32x4*)(Ab + aoff[i][ks]);
#pragma unroll
            for (int j = 0; j < 2; j++) bf[j] = *(const int32x4*)(Bb + boff[j][ks]);
#pragma unroll
            for (int i = 0; i < 4; i++)
#pragma unroll
                for (int j = 0; j < 2; j++)
                    acc[i][j] = __builtin_amdgcn_mfma_i32_32x32x32_i8(af[i], bf[j], acc[i][j], 0, 0, 0);
        }
    };

    stage(0, 0);
    __syncthreads();
#pragma unroll 1
    for (int kt = 0; kt < 4096; kt += 128) {
        stage(1, kt + 64);
        compute(0);
        __syncthreads();
        if (kt + 128 < 4096) stage(0, kt + 128);
        compute(1);
        __syncthreads();
    }

    // Epilogue. C/D: col = lane&31, row = (reg&3) + 8*(reg>>2) + 4*kh
#pragma unroll
    for (int i = 0; i < 4; i++) {
#pragma unroll
        for (int r = 0; r < 16; r++) {
            const int gm = bm + wm + i * 32 + (r & 3) + 8 * (r >> 2) + 4 * kh;
            const int rcorr = -32 * rs[gm] - 8650752;
#pragma unroll
            for (int j = 0; j < 2; j++) {
                const int gn = bn + wn + j * 32 + mr;
                const int v = acc[i][j][r] + rcorr + 66 * sy[gn];
                C[(size_t)gm * 4096 + gn] = 7.5e-4f * (float)v;
            }
        }
    }
}

// ---------------------------------------------------------------------------
extern "C" void kernel_launch(void* const* d_in, const int* in_sizes, int n_in,
                              void* d_out, int out_size, void* d_ws, size_t ws_size,
                              hipStream_t stream) {
    const float* x = (const float*)d_in[0];  // [4096,4096] int8-valued
    const float* y = (const float*)d_in[1];  // [4096,4096] uint8-valued
    float* out = (float*)d_out;

    char* ws = (char*)d_ws;
    signed char* A8  = (signed char*)ws;                         // 16 MiB
    signed char* B8T = (signed char*)(ws + (16u << 20));         // 16 MiB
    int* rs = (int*)(ws + (32u << 20));                          // 16 KiB
    int* sy = (int*)(ws + (32u << 20) + (16u << 10));            // 16 KiB

    hipMemsetAsync(sy, 0, 4096 * sizeof(int), stream);
    quant_x<<<4096, 256, 0, stream>>>(x, A8, rs);
    quant_y<<<dim3(64, 64), 256, 0, stream>>>(y, B8T, sy);
    gemm_i8<<<dim3(32, 16), 256, 0, stream>>>(A8, B8T, rs, sy, out);
}

// Round 6
// 249.471 us; speedup vs baseline: 1.0292x; 1.0203x over previous
//
#include <hip/hip_runtime.h>
#include <cstdint>
#include <cstddef>

typedef int int32x4  __attribute__((ext_vector_type(4)));
typedef int int32x16 __attribute__((ext_vector_type(16)));

#define AS1 __attribute__((address_space(1)))
#define AS3 __attribute__((address_space(3)))

__device__ __forceinline__ void gload_lds16(const void* g, void* l) {
    __builtin_amdgcn_global_load_lds((const AS1 void*)g, (AS3 void*)l, 16, 0, 0);
}

// ---------------------------------------------------------------------------
// Kernel 1: x (fp32, int8-valued) -> A8 (int8) + row sums rs.
// One block per row. Fully coalesced: loads 1KB/wave-instr, stores 256B.
// ---------------------------------------------------------------------------
__global__ __launch_bounds__(256) void quant_x(const float* __restrict__ x,
                                               signed char* __restrict__ A8,
                                               int* __restrict__ rs) {
    const int row = blockIdx.x;
    const int t = threadIdx.x;
    const float4* xr = (const float4*)(x + (size_t)row * 4096);
    char4* ar = (char4*)(A8 + (size_t)row * 4096);
    int s = 0;
#pragma unroll
    for (int i = 0; i < 4; i++) {
        const int idx = i * 256 + t;
        float4 v = xr[idx];
        int a0 = (int)v.x, a1 = (int)v.y, a2 = (int)v.z, a3 = (int)v.w;
        s += a0 + a1 + a2 + a3;
        char4 c;
        c.x = (signed char)a0; c.y = (signed char)a1;
        c.z = (signed char)a2; c.w = (signed char)a3;
        ar[idx] = c;
    }
#pragma unroll
    for (int off = 32; off > 0; off >>= 1) s += __shfl_down(s, off);
    __shared__ int wsum[4];
    if ((t & 63) == 0) wsum[t >> 6] = s;
    __syncthreads();
    if (t == 0) rs[row] = wsum[0] + wsum[1] + wsum[2] + wsum[3];
}

// ---------------------------------------------------------------------------
// Kernel 2: y (fp32, uint8-valued) -> B8T (int8 transposed, y-128) + col sums
// sy (fused; sy pre-zeroed by memset). 64k x 64n tile per block via LDS
// byte-transpose (pitch 68 -> <=2-way banks). Stores: int4, adjacent-lane
// quads cover each output row's 64B in order.
// ---------------------------------------------------------------------------
__global__ __launch_bounds__(256) void quant_y(const float* __restrict__ y,
                                               signed char* __restrict__ B8T,
                                               int* __restrict__ sy) {
    __shared__ __align__(16) signed char tile[64 * 68];  // tile[n*68 + k]
    __shared__ int ssum[64];
    const int nt = blockIdx.x * 64;
    const int kt = blockIdx.y * 64;
    const int t = threadIdx.x;
    if (t < 64) ssum[t] = 0;
    __syncthreads();

    const int r0 = t >> 4;         // k-offset within tile group
    const int c4 = (t & 15) * 4;   // n-offset (4 cols per thread)
    int s0 = 0, s1 = 0, s2 = 0, s3 = 0;
#pragma unroll
    for (int i = 0; i < 4; i++) {
        const int k = i * 16 + r0;
        float4 v = *(const float4*)(y + (size_t)(kt + k) * 4096 + nt + c4);
        int b0 = (int)v.x - 128, b1 = (int)v.y - 128;
        int b2 = (int)v.z - 128, b3 = (int)v.w - 128;
        s0 += b0; s1 += b1; s2 += b2; s3 += b3;
        tile[(c4 + 0) * 68 + k] = (signed char)b0;
        tile[(c4 + 1) * 68 + k] = (signed char)b1;
        tile[(c4 + 2) * 68 + k] = (signed char)b2;
        tile[(c4 + 3) * 68 + k] = (signed char)b3;
    }
    atomicAdd(&ssum[c4 + 0], s0);
    atomicAdd(&ssum[c4 + 1], s1);
    atomicAdd(&ssum[c4 + 2], s2);
    atomicAdd(&ssum[c4 + 3], s3);
    __syncthreads();

    const int n = t >> 2;          // output row within tile
    const int kc = (t & 3) * 16;   // 16B chunk within row
    const signed char* src = tile + n * 68 + kc;
    int32x4 w;
    w.x = *(const int*)(src + 0);
    w.y = *(const int*)(src + 4);
    w.z = *(const int*)(src + 8);
    w.w = *(const int*)(src + 12);
    *(int32x4*)(B8T + (size_t)(nt + n) * 4096 + kt + kc) = w;
    if (t < 64) atomicAdd(&sy[nt + t], ssum[t]);
}

// ---------------------------------------------------------------------------
// Kernel 3: int8 GEMM. Block tile 256(M) x 128(N), BK=64, 4 waves in 2x2,
// wave tile 128x64 = 4x2 grid of 32x32x32 i8 MFMAs.
// THREE-stage LDS pipeline with RAW s_barrier + manual s_waitcnt vmcnt(6):
// __syncthreads' implicit vmcnt(0) drain was the ~60% idle in rounds 3-5
// (all plateaued at 97us / 30% MfmaUtil regardless of tiling). Here the
// newest stage's 6 global_load_lds stay in flight across the barrier; we
// only wait for the tile staged TWO iters ago (vmcnt(6) = all but newest 6).
// Safety: wait precedes barrier, so after the barrier every wave's current
// tile is in LDS; ds_reads of a buffer complete before each wave's MFMAs
// (which precede the barrier), so staging buf (i+2)%3 can't race readers
// of tile i-1 (same buffer).
// LDS layout: dense 64B rows, XOR chunk swizzle slot = chunk ^ ((row>>1)&3).
// 32x32x32_i8 frags: A[m=lane&31][k=(lane>>5)*16+j]; C/D col=lane&31,
// row=(reg&3)+8*(reg>>2)+4*(lane>>5)  (verified rounds 1-5, absmax 32).
// Epilogue: C = 7.5e-4 * (P - 32*rs[m] + 66*sy[n] - 8650752)
// ---------------------------------------------------------------------------
__global__ __launch_bounds__(256, 2) void gemm_i8(const signed char* __restrict__ A8,
                                                  const signed char* __restrict__ B8T,
                                                  const int* __restrict__ rs,
                                                  const int* __restrict__ sy,
                                                  float* __restrict__ C) {
    __shared__ __align__(16) signed char As[3 * 16384];  // 256 rows x 64B x 3
    __shared__ __align__(16) signed char Bs[3 * 8192];   // 128 rows x 64B x 3
    const int tid = threadIdx.x;
    const int bm = blockIdx.y * 256;
    const int bn = blockIdx.x * 128;
    const int lane = tid & 63;
    const int wave = tid >> 6;
    const int wm = (wave >> 1) * 128;   // 2 m-waves x 128
    const int wn = (wave & 1) * 64;     // 2 n-waves x 64
    const int mr = lane & 31;           // row within 32x32 tile
    const int kh = lane >> 5;           // k-half (which 16B of K=32)

    int32x16 acc[4][2] = {};

    // staging: thread tid -> row (tid>>2) + 64*p (adjacent quads), global
    // chunk (tid&3)^((tid>>3)&3) lands at phys slot tid&3 (XOR swizzle).
    const int srow = tid >> 2;
    const int scol = ((tid & 3) ^ ((tid >> 3) & 3)) * 16;
    const size_t arow = (size_t)(bm + srow) * 4096 + scol;
    const size_t brow = (size_t)(bn + srow) * 4096 + scol;

    // fragment LDS offsets (K-loop invariant):
    // row = wtile + i*32 + mr; chunk = ks*2 + kh; slot = chunk ^ ((mr>>1)&3)
    int aoff[4][2], boff[2][2];
#pragma unroll
    for (int ks = 0; ks < 2; ks++) {
        const int slot = ((ks * 2 + kh) ^ ((mr >> 1) & 3)) * 16;
#pragma unroll
        for (int i = 0; i < 4; i++) aoff[i][ks] = (wm + i * 32 + mr) * 64 + slot;
#pragma unroll
        for (int j = 0; j < 2; j++) boff[j][ks] = (wn + j * 32 + mr) * 64 + slot;
    }

    auto stage = [&](int buf, int kt) {   // 6 global_load_lds per thread
        signed char* a_dst = As + buf * 16384 + tid * 16;
        signed char* b_dst = Bs + buf * 8192 + tid * 16;
#pragma unroll
        for (int p = 0; p < 4; p++)
            gload_lds16(A8 + arow + (size_t)p * 64 * 4096 + kt, a_dst + p * 4096);
#pragma unroll
        for (int p = 0; p < 2; p++)
            gload_lds16(B8T + brow + (size_t)p * 64 * 4096 + kt, b_dst + p * 4096);
    };
    auto compute = [&](int buf) {
        const signed char* Ab = As + buf * 16384;
        const signed char* Bb = Bs + buf * 8192;
#pragma unroll
        for (int ks = 0; ks < 2; ks++) {
            int32x4 af[4], bf[2];
#pragma unroll
            for (int i = 0; i < 4; i++) af[i] = *(const int32x4*)(Ab + aoff[i][ks]);
#pragma unroll
            for (int j = 0; j < 2; j++) bf[j] = *(const int32x4*)(Bb + boff[j][ks]);
#pragma unroll
            for (int i = 0; i < 4; i++)
#pragma unroll
                for (int j = 0; j < 2; j++)
                    acc[i][j] = __builtin_amdgcn_mfma_i32_32x32x32_i8(af[i], bf[j], acc[i][j], 0, 0, 0);
        }
    };

    stage(0, 0);
    stage(1, 64);
    // waitcnt imm: vmcnt[3:0]=bits0-3, vmcnt[5:4]=bits14-15, exp=0x70, lgkm=0xF00
    // 0xF76 = vmcnt(6), lgkm/exp don't-care. 0xF70 = vmcnt(0).
#pragma unroll 1
    for (int kt = 0; kt < 4096 - 64; kt += 64) {
        const int i = kt >> 6;
        __builtin_amdgcn_s_waitcnt(0xF76);   // tile i (2-old) complete; newest 6 in flight
        __builtin_amdgcn_s_barrier();        // raw barrier: NO implicit drain
        __builtin_amdgcn_sched_barrier(0);   // keep ds_reads below the barrier
        if (kt + 128 < 4096) stage((i + 2) % 3, kt + 128);
        compute(i % 3);
    }
    __builtin_amdgcn_s_waitcnt(0xF70);       // vmcnt(0): last tile landed
    __builtin_amdgcn_s_barrier();
    __builtin_amdgcn_sched_barrier(0);
    compute(63 % 3);

    // Epilogue. C/D: col = lane&31, row = (reg&3) + 8*(reg>>2) + 4*kh
#pragma unroll
    for (int i = 0; i < 4; i++) {
#pragma unroll
        for (int r = 0; r < 16; r++) {
            const int gm = bm + wm + i * 32 + (r & 3) + 8 * (r >> 2) + 4 * kh;
            const int rcorr = -32 * rs[gm] - 8650752;
#pragma unroll
            for (int j = 0; j < 2; j++) {
                const int gn = bn + wn + j * 32 + mr;
                const int v = acc[i][j][r] + rcorr + 66 * sy[gn];
                C[(size_t)gm * 4096 + gn] = 7.5e-4f * (float)v;
            }
        }
    }
}

// ---------------------------------------------------------------------------
extern "C" void kernel_launch(void* const* d_in, const int* in_sizes, int n_in,
                              void* d_out, int out_size, void* d_ws, size_t ws_size,
                              hipStream_t stream) {
    const float* x = (const float*)d_in[0];  // [4096,4096] int8-valued
    const float* y = (const float*)d_in[1];  // [4096,4096] uint8-valued
    float* out = (float*)d_out;

    char* ws = (char*)d_ws;
    signed char* A8  = (signed char*)ws;                         // 16 MiB
    signed char* B8T = (signed char*)(ws + (16u << 20));         // 16 MiB
    int* rs = (int*)(ws + (32u << 20));                          // 16 KiB
    int* sy = (int*)(ws + (32u << 20) + (16u << 10));            // 16 KiB

    hipMemsetAsync(sy, 0, 4096 * sizeof(int), stream);
    quant_x<<<4096, 256, 0, stream>>>(x, A8, rs);
    quant_y<<<dim3(64, 64), 256, 0, stream>>>(y, B8T, sy);
    gemm_i8<<<dim3(32, 16), 256, 0, stream>>>(A8, B8T, rs, sy, out);
}